// Round 9
// baseline (971.019 us; speedup 1.0000x reference)
//
#include <hip/hip_runtime.h>

#define TFULL 4092
#define NB    64
#define CH    16
#define OUT_T 2048
#define TOFF  2044
#define GNT   512

__device__ __forceinline__ int wave_first(int v) {
    return __builtin_amdgcn_readfirstlane(v);
}

// ---------------- fused group: SoA LDS planes, 2 rows/thread in one body
// sharing the s_load weight stream (32 FMA chains / weight batch).
// __launch_bounds__(512,2): ROCm treats arg2 as min-BLOCKS/CU -> VGPR cap 128
// (the (512,4) form capped at 64 and spilled -> round-8 blowup).
// Waves whose A-slab is fully inactive run a single-row body.
template<int L0, int NL, int TILE, int HALO, bool FIRSTG>
__global__ __launch_bounds__(GNT, 2) void group5_kernel(
    const float* __restrict__ input,     // (B,T,4)
    const float* __restrict__ conv_w0,   // (3,4,16)
    const float* __restrict__ conv_w,    // (17,3,19,16)
    const float* __restrict__ conv_b,    // (18,16)
    const float* __restrict__ io_w,      // (17,16,16)
    const float* __restrict__ io_b,      // (17,16)
    const float* __restrict__ mixer_w,   // (288)
    const float* __restrict__ mixer_b,   // (1)
    const float* __restrict__ sig_in,    // prev signal (B,T,16); unused if FIRSTG
    float* __restrict__ sig_out,         // group output signal (B,T,16)
    float* __restrict__ out,             // (B,2048)
    int out_start)
{
    constexpr int NROWS = TILE + HALO;
    __shared__ float4 pl0[NROWS], pl1[NROWS], pl2[NROWS], pl3[NROWS], plx[NROWS];

    const int b       = blockIdx.y;
    const int tid     = threadIdx.x;
    const int tile_lo = out_start + blockIdx.x * TILE;
    const int tile_hi = (tile_lo + TILE < TFULL) ? (tile_lo + TILE) : TFULL;
    const int buf_lo  = tile_lo - HALO;
    const int jmax    = tile_hi - buf_lo;     // valid rows [0, jmax)
    const int jA      = NROWS - 1024 + tid;   // may be < 0
    const int jB      = NROWS - 512  + tid;   // in [NROWS-512, NROWS)

    const float4* ib4 = (const float4*)(input + (size_t)b * TFULL * 4);

    for (int j = tid; j < jmax; j += GNT) {
        plx[j] = ib4[buf_lo + j];
        if constexpr (!FIRSTG) {
            const float4* row = (const float4*)(sig_in + ((size_t)b * TFULL + buf_lo + j) * CH);
            pl0[j] = row[0]; pl1[j] = row[1]; pl2[j] = row[2]; pl3[j] = row[3];
        }
    }
    __syncthreads();

    float accA = 0.f, accB = 0.f;
    float snA[CH], snB[CH];
    int lo_off = 0;

    #pragma unroll 1
    for (int i = 0; i < NL; ++i) {
        const int g   = L0 + i;
        const int dil = 1 << (g % 9);
        lo_off += 2 * dil;
        const float* wb   = (FIRSTG && i == 0) ? conv_w0
                                               : conv_w + (size_t)(g - 1) * 3 * 19 * CH;
        const float* bias = conv_b  + (size_t)g * CH;
        const float* iw   = io_w    + (size_t)g * CH * CH;
        const float* ob   = io_b    + (size_t)g * CH;
        const float* mw   = mixer_w + (size_t)g * CH;

        const bool anyB = (wave_first(jB) + 63 >= lo_off);   // B-slab has work
        const bool anyA = (wave_first(jA) + 63 >= lo_off);   // A-slab has work

        if (anyB & anyA) {
            // -------- dual-row body: one weight stream feeds 32 FMA chains --------
            float hA[CH], hB[CH];
            #pragma unroll
            for (int o = 0; o < CH; ++o) { hA[o] = bias[o]; hB[o] = bias[o]; }
            float sumA, sumB;

            if (FIRSTG && i == 0) {
                const float4 a0 = plx[max(jA - 2, 0)], a1 = plx[max(jA - 1, 0)],
                             a2 = plx[max(jA, 0)];
                const float4 b0 = plx[max(jB - 2, 0)], b1 = plx[max(jB - 1, 0)],
                             b2 = plx[jB];
                const float tA[3][4] = {{a0.x,a0.y,a0.z,a0.w},
                                        {a1.x,a1.y,a1.z,a1.w},
                                        {a2.x,a2.y,a2.z,a2.w}};
                const float tB[3][4] = {{b0.x,b0.y,b0.z,b0.w},
                                        {b1.x,b1.y,b1.z,b1.w},
                                        {b2.x,b2.y,b2.z,b2.w}};
                #pragma unroll
                for (int k = 0; k < 3; ++k) {
                    #pragma unroll
                    for (int cc = 0; cc < 4; ++cc) {
                        #pragma unroll
                        for (int o = 0; o < CH; ++o) {
                            const float wv = wb[(k * 4 + cc) * CH + o];
                            hA[o] = fmaf(tA[k][cc], wv, hA[o]);
                            hB[o] = fmaf(tB[k][cc], wv, hB[o]);
                        }
                    }
                }
                sumA = a2.x; sumB = b2.x;
            } else {
                sumA = 0.f; sumB = 0.f;
                #pragma unroll
                for (int k = 0; k < 3; ++k) {
                    const int jmA = max(jA - (2 - k) * dil, 0);
                    const int jmB = max(jB - (2 - k) * dil, 0);
                    const float4 sA0 = pl0[jmA], sA1 = pl1[jmA], sA2 = pl2[jmA], sA3 = pl3[jmA];
                    const float4 xA  = plx[jmA];
                    const float4 sB0 = pl0[jmB], sB1 = pl1[jmB], sB2 = pl2[jmB], sB3 = pl3[jmB];
                    const float4 xB  = plx[jmB];
                    if (k == 2) {
                        sumA = ((sA0.x + sA0.y) + (sA0.z + sA0.w)) + ((sA1.x + sA1.y) + (sA1.z + sA1.w))
                             + ((sA2.x + sA2.y) + (sA2.z + sA2.w)) + ((sA3.x + sA3.y) + (sA3.z + sA3.w));
                        sumB = ((sB0.x + sB0.y) + (sB0.z + sB0.w)) + ((sB1.x + sB1.y) + (sB1.z + sB1.w))
                             + ((sB2.x + sB2.y) + (sB2.z + sB2.w)) + ((sB3.x + sB3.y) + (sB3.z + sB3.w));
                    }
                    const float tvA[19] = {sA0.x,sA0.y,sA0.z,sA0.w, sA1.x,sA1.y,sA1.z,sA1.w,
                                           sA2.x,sA2.y,sA2.z,sA2.w, sA3.x,sA3.y,sA3.z,sA3.w,
                                           xA.y,xA.z,xA.w};
                    const float tvB[19] = {sB0.x,sB0.y,sB0.z,sB0.w, sB1.x,sB1.y,sB1.z,sB1.w,
                                           sB2.x,sB2.y,sB2.z,sB2.w, sB3.x,sB3.y,sB3.z,sB3.w,
                                           xB.y,xB.z,xB.w};
                    #pragma unroll
                    for (int cc = 0; cc < 19; ++cc) {
                        #pragma unroll
                        for (int o = 0; o < CH; ++o) {
                            const float wv = wb[(k * 19 + cc) * CH + o];
                            hA[o] = fmaf(tvA[cc], wv, hA[o]);
                            hB[o] = fmaf(tvB[cc], wv, hB[o]);
                        }
                    }
                }
            }
            #pragma unroll
            for (int o = 0; o < CH; ++o) { hA[o] = fmaxf(hA[o], 0.f); hB[o] = fmaxf(hB[o], 0.f); }

            if (jA >= HALO && jA < jmax && (buf_lo + jA) >= TOFF) {
                float d = 0.f;
                #pragma unroll
                for (int o = 0; o < CH; ++o) d = fmaf(hA[o], mw[o], d);
                accA += d;
            }
            if (jB >= HALO && jB < jmax && (buf_lo + jB) >= TOFF) {
                float d = 0.f;
                #pragma unroll
                for (int o = 0; o < CH; ++o) d = fmaf(hB[o], mw[o], d);
                accB += d;
            }
            const float halfA = 0.5f * sumA, halfB = 0.5f * sumB;
            #pragma unroll
            for (int o = 0; o < CH; ++o) { snA[o] = ob[o] + halfA; snB[o] = ob[o] + halfB; }
            #pragma unroll
            for (int cc = 0; cc < CH; ++cc) {
                #pragma unroll
                for (int o = 0; o < CH; ++o) {
                    const float wv = iw[cc * CH + o];
                    snA[o] = fmaf(hA[cc], wv, snA[o]);
                    snB[o] = fmaf(hB[cc], wv, snB[o]);
                }
            }
        } else if (anyB) {
            // -------- single-row body (B only); A-slab inactive this layer --------
            float hB[CH];
            #pragma unroll
            for (int o = 0; o < CH; ++o) hB[o] = bias[o];
            float sumB;
            if (FIRSTG && i == 0) {
                const float4 b0 = plx[max(jB - 2, 0)], b1 = plx[max(jB - 1, 0)],
                             b2 = plx[jB];
                const float tB[3][4] = {{b0.x,b0.y,b0.z,b0.w},
                                        {b1.x,b1.y,b1.z,b1.w},
                                        {b2.x,b2.y,b2.z,b2.w}};
                #pragma unroll
                for (int k = 0; k < 3; ++k) {
                    #pragma unroll
                    for (int cc = 0; cc < 4; ++cc) {
                        #pragma unroll
                        for (int o = 0; o < CH; ++o)
                            hB[o] = fmaf(tB[k][cc], wb[(k * 4 + cc) * CH + o], hB[o]);
                    }
                }
                sumB = b2.x;
            } else {
                sumB = 0.f;
                #pragma unroll
                for (int k = 0; k < 3; ++k) {
                    const int jmB = max(jB - (2 - k) * dil, 0);
                    const float4 sB0 = pl0[jmB], sB1 = pl1[jmB], sB2 = pl2[jmB], sB3 = pl3[jmB];
                    const float4 xB  = plx[jmB];
                    if (k == 2)
                        sumB = ((sB0.x + sB0.y) + (sB0.z + sB0.w)) + ((sB1.x + sB1.y) + (sB1.z + sB1.w))
                             + ((sB2.x + sB2.y) + (sB2.z + sB2.w)) + ((sB3.x + sB3.y) + (sB3.z + sB3.w));
                    const float tvB[19] = {sB0.x,sB0.y,sB0.z,sB0.w, sB1.x,sB1.y,sB1.z,sB1.w,
                                           sB2.x,sB2.y,sB2.z,sB2.w, sB3.x,sB3.y,sB3.z,sB3.w,
                                           xB.y,xB.z,xB.w};
                    #pragma unroll
                    for (int cc = 0; cc < 19; ++cc) {
                        #pragma unroll
                        for (int o = 0; o < CH; ++o)
                            hB[o] = fmaf(tvB[cc], wb[(k * 19 + cc) * CH + o], hB[o]);
                    }
                }
            }
            #pragma unroll
            for (int o = 0; o < CH; ++o) hB[o] = fmaxf(hB[o], 0.f);

            if (jB >= HALO && jB < jmax && (buf_lo + jB) >= TOFF) {
                float d = 0.f;
                #pragma unroll
                for (int o = 0; o < CH; ++o) d = fmaf(hB[o], mw[o], d);
                accB += d;
            }
            const float halfB = 0.5f * sumB;
            #pragma unroll
            for (int o = 0; o < CH; ++o) snB[o] = ob[o] + halfB;
            #pragma unroll
            for (int cc = 0; cc < CH; ++cc) {
                #pragma unroll
                for (int o = 0; o < CH; ++o)
                    snB[o] = fmaf(hB[cc], iw[cc * CH + o], snB[o]);
            }
        }

        if (i != NL - 1) {
            __syncthreads();                            // reads done
            if (jB >= lo_off && jB < jmax) {
                pl0[jB] = make_float4(snB[0],  snB[1],  snB[2],  snB[3]);
                pl1[jB] = make_float4(snB[4],  snB[5],  snB[6],  snB[7]);
                pl2[jB] = make_float4(snB[8],  snB[9],  snB[10], snB[11]);
                pl3[jB] = make_float4(snB[12], snB[13], snB[14], snB[15]);
            }
            if (jA >= lo_off && jA < jmax) {
                pl0[jA] = make_float4(snA[0],  snA[1],  snA[2],  snA[3]);
                pl1[jA] = make_float4(snA[4],  snA[5],  snA[6],  snA[7]);
                pl2[jA] = make_float4(snA[8],  snA[9],  snA[10], snA[11]);
                pl3[jA] = make_float4(snA[12], snA[13], snA[14], snA[15]);
            }
            __syncthreads();                            // writes visible
        } else {
            if (jB >= HALO && jB < jmax) {              // mains -> global signal
                float* gp = sig_out + ((size_t)b * TFULL + (buf_lo + jB)) * CH;
                *(float4*)(gp + 0)  = make_float4(snB[0],  snB[1],  snB[2],  snB[3]);
                *(float4*)(gp + 4)  = make_float4(snB[4],  snB[5],  snB[6],  snB[7]);
                *(float4*)(gp + 8)  = make_float4(snB[8],  snB[9],  snB[10], snB[11]);
                *(float4*)(gp + 12) = make_float4(snB[12], snB[13], snB[14], snB[15]);
            }
            if (jA >= HALO && jA < jmax) {
                float* gp = sig_out + ((size_t)b * TFULL + (buf_lo + jA)) * CH;
                *(float4*)(gp + 0)  = make_float4(snA[0],  snA[1],  snA[2],  snA[3]);
                *(float4*)(gp + 4)  = make_float4(snA[4],  snA[5],  snA[6],  snA[7]);
                *(float4*)(gp + 8)  = make_float4(snA[8],  snA[9],  snA[10], snA[11]);
                *(float4*)(gp + 12) = make_float4(snA[12], snA[13], snA[14], snA[15]);
            }
        }
    }

    if (jA >= HALO && jA < jmax && (buf_lo + jA) >= TOFF) {
        const size_t oi = (size_t)b * OUT_T + (buf_lo + jA - TOFF);
        if constexpr (FIRSTG) out[oi] = mixer_b[0] + accA; else out[oi] += accA;
    }
    if (jB >= HALO && jB < jmax && (buf_lo + jB) >= TOFF) {
        const size_t oi = (size_t)b * OUT_T + (buf_lo + jB - TOFF);
        if constexpr (FIRSTG) out[oi] = mixer_b[0] + accB; else out[oi] += accB;
    }
}

// ---------------- unfused single layer: 2 t-rows per thread, shared weights ----------------
template<bool LASTL>
__global__ __launch_bounds__(256, 2) void single2_layer(
    const float* __restrict__ input,    // (B,T,4)
    const float* __restrict__ sig_in,   // (B,T,16)
    const float* __restrict__ w,        // (3,19,16)
    const float* __restrict__ bias,     // (16)
    const float* __restrict__ iw,       // (16,16)   unused if LASTL
    const float* __restrict__ iob,      // (16)      unused if LASTL
    const float* __restrict__ mw,       // (16)
    float* __restrict__ sig_out,        // (B,T,16)  unused if LASTL
    float* __restrict__ out,            // (B,2048)
    int dil, int t0, int S)             // rows A: t0+blk*256+tid ; rows B: A+S
{
    const int b  = blockIdx.y;
    const int tA = t0 + blockIdx.x * 256 + threadIdx.x;       // < t0+S <= TFULL
    const int tBr = tA + S;
    const bool vB = (tBr < TFULL);
    const int tB = vB ? tBr : (TFULL - 1);
    const float* ib = input  + (size_t)b * TFULL * 4;
    const float* sb = sig_in + (size_t)b * TFULL * CH;

    float hA[CH], hB[CH];
    #pragma unroll
    for (int o = 0; o < CH; ++o) { hA[o] = bias[o]; hB[o] = bias[o]; }
    float sumA = 0.f, sumB = 0.f;

    #pragma unroll
    for (int k = 0; k < 3; ++k) {
        const int dA = tA - (2 - k) * dil;
        const int dB = tB - (2 - k) * dil;
        const float4* spA = (const float4*)(sb + (size_t)dA * CH);
        const float4* spB = (const float4*)(sb + (size_t)dB * CH);
        const float4 sA0 = spA[0], sA1 = spA[1], sA2 = spA[2], sA3 = spA[3];
        const float4 sB0 = spB[0], sB1 = spB[1], sB2 = spB[2], sB3 = spB[3];
        const float4 xA = *(const float4*)(ib + (size_t)dA * 4);
        const float4 xB = *(const float4*)(ib + (size_t)dB * 4);
        if (k == 2) {
            sumA = ((sA0.x + sA0.y) + (sA0.z + sA0.w)) + ((sA1.x + sA1.y) + (sA1.z + sA1.w))
                 + ((sA2.x + sA2.y) + (sA2.z + sA2.w)) + ((sA3.x + sA3.y) + (sA3.z + sA3.w));
            sumB = ((sB0.x + sB0.y) + (sB0.z + sB0.w)) + ((sB1.x + sB1.y) + (sB1.z + sB1.w))
                 + ((sB2.x + sB2.y) + (sB2.z + sB2.w)) + ((sB3.x + sB3.y) + (sB3.z + sB3.w));
        }
        const float tvA[19] = {sA0.x,sA0.y,sA0.z,sA0.w, sA1.x,sA1.y,sA1.z,sA1.w,
                               sA2.x,sA2.y,sA2.z,sA2.w, sA3.x,sA3.y,sA3.z,sA3.w,
                               xA.y,xA.z,xA.w};
        const float tvB[19] = {sB0.x,sB0.y,sB0.z,sB0.w, sB1.x,sB1.y,sB1.z,sB1.w,
                               sB2.x,sB2.y,sB2.z,sB2.w, sB3.x,sB3.y,sB3.z,sB3.w,
                               xB.y,xB.z,xB.w};
        #pragma unroll
        for (int cc = 0; cc < 19; ++cc) {
            #pragma unroll
            for (int o = 0; o < CH; ++o) {
                const float wv = w[(k * 19 + cc) * CH + o];
                hA[o] = fmaf(tvA[cc], wv, hA[o]);
                hB[o] = fmaf(tvB[cc], wv, hB[o]);
            }
        }
    }
    #pragma unroll
    for (int o = 0; o < CH; ++o) { hA[o] = fmaxf(hA[o], 0.f); hB[o] = fmaxf(hB[o], 0.f); }

    if (tA >= TOFF) {
        float m = 0.f;
        #pragma unroll
        for (int o = 0; o < CH; ++o) m = fmaf(hA[o], mw[o], m);
        out[(size_t)b * OUT_T + (tA - TOFF)] += m;
    }
    if (vB && tB >= TOFF) {
        float m = 0.f;
        #pragma unroll
        for (int o = 0; o < CH; ++o) m = fmaf(hB[o], mw[o], m);
        out[(size_t)b * OUT_T + (tB - TOFF)] += m;
    }

    if constexpr (!LASTL) {
        float snA[CH], snB[CH];
        const float halfA = 0.5f * sumA, halfB = 0.5f * sumB;
        #pragma unroll
        for (int o = 0; o < CH; ++o) { snA[o] = iob[o] + halfA; snB[o] = iob[o] + halfB; }
        #pragma unroll
        for (int cc = 0; cc < CH; ++cc) {
            #pragma unroll
            for (int o = 0; o < CH; ++o) {
                const float wv = iw[cc * CH + o];
                snA[o] = fmaf(hA[cc], wv, snA[o]);
                snB[o] = fmaf(hB[cc], wv, snB[o]);
            }
        }
        {
            float* gp = sig_out + ((size_t)b * TFULL + tA) * CH;
            *(float4*)(gp + 0)  = make_float4(snA[0],  snA[1],  snA[2],  snA[3]);
            *(float4*)(gp + 4)  = make_float4(snA[4],  snA[5],  snA[6],  snA[7]);
            *(float4*)(gp + 8)  = make_float4(snA[8],  snA[9],  snA[10], snA[11]);
            *(float4*)(gp + 12) = make_float4(snA[12], snA[13], snA[14], snA[15]);
        }
        if (vB) {
            float* gp = sig_out + ((size_t)b * TFULL + tB) * CH;
            *(float4*)(gp + 0)  = make_float4(snB[0],  snB[1],  snB[2],  snB[3]);
            *(float4*)(gp + 4)  = make_float4(snB[4],  snB[5],  snB[6],  snB[7]);
            *(float4*)(gp + 8)  = make_float4(snB[8],  snB[9],  snB[10], snB[11]);
            *(float4*)(gp + 12) = make_float4(snB[12], snB[13], snB[14], snB[15]);
        }
    }
}

extern "C" void kernel_launch(void* const* d_in, const int* in_sizes, int n_in,
                              void* d_out, int out_size, void* d_ws, size_t ws_size,
                              hipStream_t stream) {
    const float* input   = (const float*)d_in[0];
    const float* conv_w0 = (const float*)d_in[1];
    const float* conv_w  = (const float*)d_in[2];
    const float* conv_b  = (const float*)d_in[3];
    const float* io_w    = (const float*)d_in[4];
    const float* io_b    = (const float*)d_in[5];
    const float* mixer_w = (const float*)d_in[6];
    const float* mixer_b = (const float*)d_in[7];
    float* out = (float*)d_out;

    float* s1 = (float*)d_ws;
    float* s2 = s1 + (size_t)NB * TFULL * CH;

    auto wl  = [&](int g) { return conv_w + (size_t)(g - 1) * 3 * 19 * CH; };
    auto bsl = [&](int g) { return conv_b + (size_t)g * CH; };
    auto iwl = [&](int g) { return io_w + (size_t)g * CH * CH; };
    auto ibl = [&](int g) { return io_b + (size_t)g * CH; };
    auto mwl = [&](int g) { return mixer_w + (size_t)g * CH; };

    dim3 blkG(GNT, 1, 1), blk256(256, 1, 1);

    // G_A: layers 0..6 (dil 1..64), halo 254, TILE 480, mains [254,4092)
    group5_kernel<0, 7, 480, 254, true><<<dim3(8, NB), blkG, 0, stream>>>(
        input, conv_w0, conv_w, conv_b, io_w, io_b, mixer_w, mixer_b,
        nullptr, s1, out, 254);
    // L7 (dil 128): t in [510,4092), N=3582 -> 7 blocks, S=1792 ; s1 -> s2
    single2_layer<false><<<dim3(7, NB), blk256, 0, stream>>>(
        input, s1, wl(7), bsl(7), iwl(7), ibl(7), mwl(7), s2, out, 128, 510, 1792);
    // L8 (dil 256): t in [1022,4092), N=3070 -> 6 blocks, S=1536 ; s2 -> s1
    single2_layer<false><<<dim3(6, NB), blk256, 0, stream>>>(
        input, s2, wl(8), bsl(8), iwl(8), ibl(8), mwl(8), s1, out, 256, 1022, 1536);
    // G_D: layers 9..15 (dil 1..64), halo 254, TILE 352, mains [1276,4092)
    group5_kernel<9, 7, 352, 254, false><<<dim3(8, NB), blkG, 0, stream>>>(
        input, conv_w0, conv_w, conv_b, io_w, io_b, mixer_w, mixer_b,
        s1, s2, out, 1276);
    // L16 (dil 128): t in [1532,4092), N=2560 -> 5 blocks, S=1280 ; s2 -> s1
    single2_layer<false><<<dim3(5, NB), blk256, 0, stream>>>(
        input, s2, wl(16), bsl(16), iwl(16), ibl(16), mwl(16), s1, out, 128, 1532, 1280);
    // L17 (dil 256): t in [2044,4092), N=2048 -> 4 blocks, S=1024 ; s1 -> out only
    single2_layer<true><<<dim3(4, NB), blk256, 0, stream>>>(
        input, s1, wl(17), bsl(17), nullptr, nullptr, mwl(17), nullptr, out, 256, 2044, 1024);
}

// Round 10
// 378.517 us; speedup vs baseline: 2.5653x; 2.5653x over previous
//
#include <hip/hip_runtime.h>

#define TFULL 4092
#define NB    64
#define CH    16
#define OUT_T 2048
#define TOFF  2044
#define GNT   512

__device__ __forceinline__ int wave_first(int v) {
    return __builtin_amdgcn_readfirstlane(v);
}

// ---------------- fused group: SoA LDS planes, 2 row-slabs/thread, wave-uniform
// activity guards (s_load-friendly), clamped-tap garbage rows, per-lane
// guarded writes. Single-row body per slab (VGPR ~52, spill-free — R7-proven).
template<int L0, int NL, int TILE, int HALO, bool FIRSTG>
__global__ __launch_bounds__(GNT, 4) void group3_kernel(
    const float* __restrict__ input,     // (B,T,4)
    const float* __restrict__ conv_w0,   // (3,4,16)
    const float* __restrict__ conv_w,    // (17,3,19,16)
    const float* __restrict__ conv_b,    // (18,16)
    const float* __restrict__ io_w,      // (17,16,16)
    const float* __restrict__ io_b,      // (17,16)
    const float* __restrict__ mixer_w,   // (288)
    const float* __restrict__ mixer_b,   // (1)
    const float* __restrict__ sig_in,    // prev signal (B,T,16); unused if FIRSTG
    float* __restrict__ sig_out,         // group output signal (B,T,16)
    float* __restrict__ out,             // (B,2048)
    int out_start)
{
    constexpr int NROWS = TILE + HALO;
    __shared__ float4 pl0[NROWS], pl1[NROWS], pl2[NROWS], pl3[NROWS], plx[NROWS];

    const int b       = blockIdx.y;
    const int tid     = threadIdx.x;
    const int tile_lo = out_start + blockIdx.x * TILE;
    const int tile_hi = (tile_lo + TILE < TFULL) ? (tile_lo + TILE) : TFULL;
    const int buf_lo  = tile_lo - HALO;
    const int jmax    = tile_hi - buf_lo;     // valid rows [0, jmax)
    const int j0      = NROWS - 1024 + tid;   // may be < 0
    const int j1      = NROWS - 512  + tid;

    const float4* ib4 = (const float4*)(input + (size_t)b * TFULL * 4);

    for (int j = tid; j < jmax; j += GNT) {
        plx[j] = ib4[buf_lo + j];
        if constexpr (!FIRSTG) {
            const float4* row = (const float4*)(sig_in + ((size_t)b * TFULL + buf_lo + j) * CH);
            pl0[j] = row[0]; pl1[j] = row[1]; pl2[j] = row[2]; pl3[j] = row[3];
        }
    }
    __syncthreads();

    float acc0 = 0.f, acc1 = 0.f;
    float sn0[CH], sn1[CH];
    int lo_off = 0;

    #pragma unroll 1
    for (int i = 0; i < NL; ++i) {
        const int g   = L0 + i;
        const int dil = 1 << (g % 9);
        lo_off += 2 * dil;
        const float* wb   = (FIRSTG && i == 0) ? conv_w0
                                               : conv_w + (size_t)(g - 1) * 3 * 19 * CH;
        const float* bias = conv_b  + (size_t)g * CH;
        const float* iw   = io_w    + (size_t)g * CH * CH;
        const float* ob   = io_b    + (size_t)g * CH;
        const float* mw   = mixer_w + (size_t)g * CH;

        auto do_row = [&](int j, float* sn, float& acc) {
            float h[CH];
            #pragma unroll
            for (int o = 0; o < CH; ++o) h[o] = bias[o];
            float sum;
            if (FIRSTG && i == 0) {
                const float4 x0 = plx[max(j - 2, 0)];
                const float4 x1 = plx[max(j - 1, 0)];
                const float4 x2 = plx[max(j, 0)];
                const float t0[4] = {x0.x, x0.y, x0.z, x0.w};
                const float t1[4] = {x1.x, x1.y, x1.z, x1.w};
                const float t2[4] = {x2.x, x2.y, x2.z, x2.w};
                #pragma unroll
                for (int cc = 0; cc < 4; ++cc) {
                    #pragma unroll
                    for (int o = 0; o < CH; ++o) {
                        h[o] = fmaf(t0[cc], wb[(0 * 4 + cc) * CH + o], h[o]);
                        h[o] = fmaf(t1[cc], wb[(1 * 4 + cc) * CH + o], h[o]);
                        h[o] = fmaf(t2[cc], wb[(2 * 4 + cc) * CH + o], h[o]);
                    }
                }
                sum = x2.x;
            } else {
                sum = 0.f;
                #pragma unroll
                for (int k = 0; k < 3; ++k) {
                    const int jm = max(j - (2 - k) * dil, 0);
                    const float4 s0 = pl0[jm], s1 = pl1[jm], s2 = pl2[jm], s3 = pl3[jm];
                    const float4 x  = plx[jm];
                    if (k == 2)
                        sum = ((s0.x + s0.y) + (s0.z + s0.w)) + ((s1.x + s1.y) + (s1.z + s1.w))
                            + ((s2.x + s2.y) + (s2.z + s2.w)) + ((s3.x + s3.y) + (s3.z + s3.w));
                    const float tv[19] = {s0.x, s0.y, s0.z, s0.w, s1.x, s1.y, s1.z, s1.w,
                                          s2.x, s2.y, s2.z, s2.w, s3.x, s3.y, s3.z, s3.w,
                                          x.y, x.z, x.w};
                    #pragma unroll
                    for (int cc = 0; cc < 19; ++cc) {
                        #pragma unroll
                        for (int o = 0; o < CH; ++o)
                            h[o] = fmaf(tv[cc], wb[(k * 19 + cc) * CH + o], h[o]);
                    }
                }
            }
            #pragma unroll
            for (int o = 0; o < CH; ++o) h[o] = fmaxf(h[o], 0.f);

            const int r = buf_lo + j;
            if (j >= HALO && j < jmax && r >= TOFF) {   // mixer: valid mains only
                float d = 0.f;
                #pragma unroll
                for (int o = 0; o < CH; ++o) d = fmaf(h[o], mw[o], d);
                acc += d;
            }
            const float half = 0.5f * sum;              // io -> next signal
            #pragma unroll
            for (int o = 0; o < CH; ++o) sn[o] = ob[o] + half;
            #pragma unroll
            for (int cc = 0; cc < CH; ++cc) {
                #pragma unroll
                for (int o = 0; o < CH; ++o)
                    sn[o] = fmaf(h[cc], iw[cc * CH + o], sn[o]);
            }
        };

        // wave-uniform activity (readfirstlane -> SGPR branch -> s_load weights)
        const bool w1 = (wave_first(j1) + 63 >= lo_off);
        const bool w0 = (wave_first(j0) + 63 >= lo_off);
        if (w1) do_row(j1, sn1, acc1);
        if (w0) do_row(j0, sn0, acc0);

        if (i != NL - 1) {
            __syncthreads();                            // reads done
            if (w1 && j1 >= lo_off && j1 < jmax) {
                pl0[j1] = make_float4(sn1[0],  sn1[1],  sn1[2],  sn1[3]);
                pl1[j1] = make_float4(sn1[4],  sn1[5],  sn1[6],  sn1[7]);
                pl2[j1] = make_float4(sn1[8],  sn1[9],  sn1[10], sn1[11]);
                pl3[j1] = make_float4(sn1[12], sn1[13], sn1[14], sn1[15]);
            }
            if (w0 && j0 >= lo_off && j0 < jmax) {
                pl0[j0] = make_float4(sn0[0],  sn0[1],  sn0[2],  sn0[3]);
                pl1[j0] = make_float4(sn0[4],  sn0[5],  sn0[6],  sn0[7]);
                pl2[j0] = make_float4(sn0[8],  sn0[9],  sn0[10], sn0[11]);
                pl3[j0] = make_float4(sn0[12], sn0[13], sn0[14], sn0[15]);
            }
            __syncthreads();                            // writes visible
        } else {
            if (j1 >= HALO && j1 < jmax) {              // mains -> global signal
                float* gp = sig_out + ((size_t)b * TFULL + (buf_lo + j1)) * CH;
                *(float4*)(gp + 0)  = make_float4(sn1[0],  sn1[1],  sn1[2],  sn1[3]);
                *(float4*)(gp + 4)  = make_float4(sn1[4],  sn1[5],  sn1[6],  sn1[7]);
                *(float4*)(gp + 8)  = make_float4(sn1[8],  sn1[9],  sn1[10], sn1[11]);
                *(float4*)(gp + 12) = make_float4(sn1[12], sn1[13], sn1[14], sn1[15]);
            }
            if (j0 >= HALO && j0 < jmax) {
                float* gp = sig_out + ((size_t)b * TFULL + (buf_lo + j0)) * CH;
                *(float4*)(gp + 0)  = make_float4(sn0[0],  sn0[1],  sn0[2],  sn0[3]);
                *(float4*)(gp + 4)  = make_float4(sn0[4],  sn0[5],  sn0[6],  sn0[7]);
                *(float4*)(gp + 8)  = make_float4(sn0[8],  sn0[9],  sn0[10], sn0[11]);
                *(float4*)(gp + 12) = make_float4(sn0[12], sn0[13], sn0[14], sn0[15]);
            }
        }
    }

    if (j0 >= HALO && j0 < jmax) {
        const int r = buf_lo + j0;
        if (r >= TOFF) {
            const size_t oi = (size_t)b * OUT_T + (r - TOFF);
            if constexpr (FIRSTG) out[oi] = mixer_b[0] + acc0; else out[oi] += acc0;
        }
    }
    if (j1 >= HALO && j1 < jmax) {
        const int r = buf_lo + j1;
        if (r >= TOFF) {
            const size_t oi = (size_t)b * OUT_T + (r - TOFF);
            if constexpr (FIRSTG) out[oi] = mixer_b[0] + acc1; else out[oi] += acc1;
        }
    }
}

// ---------------- unfused single layer (big dilation, zero halo), de-diverged ----------------
template<bool LASTL>
__global__ __launch_bounds__(256, 4) void single_layer(
    const float* __restrict__ input,    // (B,T,4)
    const float* __restrict__ sig_in,   // (B,T,16)
    const float* __restrict__ w,        // (3,19,16)
    const float* __restrict__ bias,     // (16)
    const float* __restrict__ iw,       // (16,16)   unused if LASTL
    const float* __restrict__ iob,      // (16)      unused if LASTL
    const float* __restrict__ mw,       // (16)
    float* __restrict__ sig_out,        // (B,T,16)  unused if LASTL
    float* __restrict__ out,            // (B,2048)
    int dil, int t0)
{
    const int b    = blockIdx.y;
    const int traw = t0 + blockIdx.x * 256 + threadIdx.x;
    const int t    = (traw < TFULL) ? traw : (TFULL - 1);   // clamp, guard stores
    const float* ib = input  + (size_t)b * TFULL * 4;
    const float* sb = sig_in + (size_t)b * TFULL * CH;

    const int tt0 = t - 2 * dil, tt1 = t - dil;
    const float4* sp0 = (const float4*)(sb + (size_t)tt0 * CH);
    const float4* sp1 = (const float4*)(sb + (size_t)tt1 * CH);
    const float4* sp2 = (const float4*)(sb + (size_t)t   * CH);
    const float4 a0 = sp0[0], a1 = sp0[1], a2 = sp0[2], a3 = sp0[3];
    const float4 b0 = sp1[0], b1 = sp1[1], b2 = sp1[2], b3 = sp1[3];
    const float4 c0 = sp2[0], c1 = sp2[1], c2 = sp2[2], c3 = sp2[3];
    const float4 x0 = *(const float4*)(ib + (size_t)tt0 * 4);
    const float4 x1 = *(const float4*)(ib + (size_t)tt1 * 4);
    const float4 x2 = *(const float4*)(ib + (size_t)t   * 4);

    float h[CH];
    #pragma unroll
    for (int o = 0; o < CH; ++o) h[o] = bias[o];

    const float t0v[19] = {a0.x,a0.y,a0.z,a0.w, a1.x,a1.y,a1.z,a1.w,
                           a2.x,a2.y,a2.z,a2.w, a3.x,a3.y,a3.z,a3.w,
                           x0.y,x0.z,x0.w};
    const float t1v[19] = {b0.x,b0.y,b0.z,b0.w, b1.x,b1.y,b1.z,b1.w,
                           b2.x,b2.y,b2.z,b2.w, b3.x,b3.y,b3.z,b3.w,
                           x1.y,x1.z,x1.w};
    const float t2v[19] = {c0.x,c0.y,c0.z,c0.w, c1.x,c1.y,c1.z,c1.w,
                           c2.x,c2.y,c2.z,c2.w, c3.x,c3.y,c3.z,c3.w,
                           x2.y,x2.z,x2.w};
    #pragma unroll
    for (int cc = 0; cc < 19; ++cc) {
        #pragma unroll
        for (int o = 0; o < CH; ++o) {
            h[o] = fmaf(t0v[cc], w[(0 * 19 + cc) * CH + o], h[o]);
            h[o] = fmaf(t1v[cc], w[(1 * 19 + cc) * CH + o], h[o]);
            h[o] = fmaf(t2v[cc], w[(2 * 19 + cc) * CH + o], h[o]);
        }
    }
    #pragma unroll
    for (int o = 0; o < CH; ++o) h[o] = fmaxf(h[o], 0.f);

    if (traw < TFULL && traw >= TOFF) {
        float m = 0.f;
        #pragma unroll
        for (int o = 0; o < CH; ++o) m = fmaf(h[o], mw[o], m);
        out[(size_t)b * OUT_T + (traw - TOFF)] += m;
    }

    if constexpr (!LASTL) {
        const float sum_t = ((c0.x + c0.y) + (c0.z + c0.w)) + ((c1.x + c1.y) + (c1.z + c1.w))
                          + ((c2.x + c2.y) + (c2.z + c2.w)) + ((c3.x + c3.y) + (c3.z + c3.w));
        float sn[CH];
        const float half = 0.5f * sum_t;
        #pragma unroll
        for (int o = 0; o < CH; ++o) sn[o] = iob[o] + half;
        #pragma unroll
        for (int cc = 0; cc < CH; ++cc) {
            #pragma unroll
            for (int o = 0; o < CH; ++o)
                sn[o] = fmaf(h[cc], iw[cc * CH + o], sn[o]);
        }
        if (traw < TFULL) {
            float* gp = sig_out + ((size_t)b * TFULL + traw) * CH;
            *(float4*)(gp + 0)  = make_float4(sn[0],  sn[1],  sn[2],  sn[3]);
            *(float4*)(gp + 4)  = make_float4(sn[4],  sn[5],  sn[6],  sn[7]);
            *(float4*)(gp + 8)  = make_float4(sn[8],  sn[9],  sn[10], sn[11]);
            *(float4*)(gp + 12) = make_float4(sn[12], sn[13], sn[14], sn[15]);
        }
    }
}

extern "C" void kernel_launch(void* const* d_in, const int* in_sizes, int n_in,
                              void* d_out, int out_size, void* d_ws, size_t ws_size,
                              hipStream_t stream) {
    const float* input   = (const float*)d_in[0];
    const float* conv_w0 = (const float*)d_in[1];
    const float* conv_w  = (const float*)d_in[2];
    const float* conv_b  = (const float*)d_in[3];
    const float* io_w    = (const float*)d_in[4];
    const float* io_b    = (const float*)d_in[5];
    const float* mixer_w = (const float*)d_in[6];
    const float* mixer_b = (const float*)d_in[7];
    float* out = (float*)d_out;

    float* s1 = (float*)d_ws;
    float* s2 = s1 + (size_t)NB * TFULL * CH;

    auto wl  = [&](int g) { return conv_w + (size_t)(g - 1) * 3 * 19 * CH; };
    auto bsl = [&](int g) { return conv_b + (size_t)g * CH; };
    auto iwl = [&](int g) { return io_w + (size_t)g * CH * CH; };
    auto ibl = [&](int g) { return io_b + (size_t)g * CH; };
    auto mwl = [&](int g) { return mixer_w + (size_t)g * CH; };

    dim3 blkG(GNT, 1, 1), blk256(256, 1, 1);

    // G_A: layers 0..6 (dil 1..64), halo 254, TILE 320 -> 12 tiles, mains [254,4092)
    // LDS 45.9KB -> 3 blocks/CU; grid 768 = 3/CU (was 2/CU at TILE 480).
    group3_kernel<0, 7, 320, 254, true><<<dim3(12, NB), blkG, 0, stream>>>(
        input, conv_w0, conv_w, conv_b, io_w, io_b, mixer_w, mixer_b,
        nullptr, s1, out, 254);
    // L7 (dil 128): t in [510,4092) ; s1 -> s2
    single_layer<false><<<dim3(14, NB), blk256, 0, stream>>>(
        input, s1, wl(7), bsl(7), iwl(7), ibl(7), mwl(7), s2, out, 128, 510);
    // L8 (dil 256): t in [1022,4092) ; s2 -> s1
    single_layer<false><<<dim3(12, NB), blk256, 0, stream>>>(
        input, s2, wl(8), bsl(8), iwl(8), ibl(8), mwl(8), s1, out, 256, 1022);
    // G_D: layers 9..15 (dil 1..64), halo 254, TILE 256 -> 11 tiles (2816 exact),
    // mains [1276,4092); LDS 40.8KB; grid 704 = 2.75/CU (was 2/CU at TILE 352).
    group3_kernel<9, 7, 256, 254, false><<<dim3(11, NB), blkG, 0, stream>>>(
        input, conv_w0, conv_w, conv_b, io_w, io_b, mixer_w, mixer_b,
        s1, s2, out, 1276);
    // L16 (dil 128): t in [1532,4092) ; s2 -> s1
    single_layer<false><<<dim3(10, NB), blk256, 0, stream>>>(
        input, s2, wl(16), bsl(16), iwl(16), ibl(16), mwl(16), s1, out, 128, 1532);
    // L17 (dil 256): t in [2044,4092) ; s1 -> out only
    single_layer<true><<<dim3(8, NB), blk256, 0, stream>>>(
        input, s1, wl(17), bsl(17), nullptr, nullptr, mwl(17), nullptr, out, 256, 2044);
}

// Round 11
// 296.655 us; speedup vs baseline: 3.2732x; 1.2760x over previous
//
#include <hip/hip_runtime.h>

#define TFULL 4092
#define NB    64
#define CH    16
#define OUT_T 2048
#define TOFF  2044
#define GNT   512

__device__ __forceinline__ int wave_first(int v) {
    return __builtin_amdgcn_readfirstlane(v);
}

// ---------------- fused group: SoA LDS planes, 2 row-slabs/thread, wave-uniform
// activity guards, clamped-tap garbage rows, per-lane guarded writes.
// NEW vs R7: the k=2 (own-row) tap is fed from the persistent sn registers
// (the same thread computed that row last layer) -> 4 fewer ds_read_b128 and
// no re-sum per row-layer. Tiling/grid/barriers identical to R7 (295us best).
template<int L0, int NL, int TILE, int HALO, bool FIRSTG>
__global__ __launch_bounds__(GNT, 4) void group6_kernel(
    const float* __restrict__ input,     // (B,T,4)
    const float* __restrict__ conv_w0,   // (3,4,16)
    const float* __restrict__ conv_w,    // (17,3,19,16)
    const float* __restrict__ conv_b,    // (18,16)
    const float* __restrict__ io_w,      // (17,16,16)
    const float* __restrict__ io_b,      // (17,16)
    const float* __restrict__ mixer_w,   // (288)
    const float* __restrict__ mixer_b,   // (1)
    const float* __restrict__ sig_in,    // prev signal (B,T,16); unused if FIRSTG
    float* __restrict__ sig_out,         // group output signal (B,T,16)
    float* __restrict__ out,             // (B,2048)
    int out_start)
{
    constexpr int NROWS = TILE + HALO;
    __shared__ float4 pl0[NROWS], pl1[NROWS], pl2[NROWS], pl3[NROWS], plx[NROWS];

    const int b       = blockIdx.y;
    const int tid     = threadIdx.x;
    const int tile_lo = out_start + blockIdx.x * TILE;
    const int tile_hi = (tile_lo + TILE < TFULL) ? (tile_lo + TILE) : TFULL;
    const int buf_lo  = tile_lo - HALO;
    const int jmax    = tile_hi - buf_lo;     // valid rows [0, jmax)
    const int j0      = NROWS - 1024 + tid;   // may be < 0
    const int j1      = NROWS - 512  + tid;   // always in [0, NROWS)

    const float4* ib4 = (const float4*)(input + (size_t)b * TFULL * 4);

    for (int j = tid; j < jmax; j += GNT) {
        plx[j] = ib4[buf_lo + j];
        if constexpr (!FIRSTG) {
            const float4* row = (const float4*)(sig_in + ((size_t)b * TFULL + buf_lo + j) * CH);
            pl0[j] = row[0]; pl1[j] = row[1]; pl2[j] = row[2]; pl3[j] = row[3];
        }
    }
    __syncthreads();

    float acc0 = 0.f, acc1 = 0.f;
    float sn0[CH], sn1[CH];

    if constexpr (!FIRSTG) {
        // init own-row signal registers from the staged planes
        const int c0 = (j0 > 0) ? j0 : 0;
        {
            const float4 a = pl0[c0], bq = pl1[c0], c = pl2[c0], d = pl3[c0];
            sn0[0]=a.x; sn0[1]=a.y; sn0[2]=a.z; sn0[3]=a.w;
            sn0[4]=bq.x; sn0[5]=bq.y; sn0[6]=bq.z; sn0[7]=bq.w;
            sn0[8]=c.x; sn0[9]=c.y; sn0[10]=c.z; sn0[11]=c.w;
            sn0[12]=d.x; sn0[13]=d.y; sn0[14]=d.z; sn0[15]=d.w;
        }
        {
            const float4 a = pl0[j1], bq = pl1[j1], c = pl2[j1], d = pl3[j1];
            sn1[0]=a.x; sn1[1]=a.y; sn1[2]=a.z; sn1[3]=a.w;
            sn1[4]=bq.x; sn1[5]=bq.y; sn1[6]=bq.z; sn1[7]=bq.w;
            sn1[8]=c.x; sn1[9]=c.y; sn1[10]=c.z; sn1[11]=c.w;
            sn1[12]=d.x; sn1[13]=d.y; sn1[14]=d.z; sn1[15]=d.w;
        }
    }

    int lo_off = 0;

    #pragma unroll 1
    for (int i = 0; i < NL; ++i) {
        const int g   = L0 + i;
        const int dil = 1 << (g % 9);
        lo_off += 2 * dil;
        const float* wb   = (FIRSTG && i == 0) ? conv_w0
                                               : conv_w + (size_t)(g - 1) * 3 * 19 * CH;
        const float* bias = conv_b  + (size_t)g * CH;
        const float* iw   = io_w    + (size_t)g * CH * CH;
        const float* ob   = io_b    + (size_t)g * CH;
        const float* mw   = mixer_w + (size_t)g * CH;

        // sn holds this row's CURRENT-layer input (own-row k=2 tap), in regs.
        auto do_row = [&](int j, float* sn, float& acc) {
            float h[CH];
            #pragma unroll
            for (int o = 0; o < CH; ++o) h[o] = bias[o];
            float sum;
            if (FIRSTG && i == 0) {
                const float4 x0 = plx[max(j - 2, 0)];
                const float4 x1 = plx[max(j - 1, 0)];
                const float4 x2 = plx[max(j, 0)];
                const float t0[4] = {x0.x, x0.y, x0.z, x0.w};
                const float t1[4] = {x1.x, x1.y, x1.z, x1.w};
                const float t2[4] = {x2.x, x2.y, x2.z, x2.w};
                #pragma unroll
                for (int cc = 0; cc < 4; ++cc) {
                    #pragma unroll
                    for (int o = 0; o < CH; ++o) {
                        h[o] = fmaf(t0[cc], wb[(0 * 4 + cc) * CH + o], h[o]);
                        h[o] = fmaf(t1[cc], wb[(1 * 4 + cc) * CH + o], h[o]);
                        h[o] = fmaf(t2[cc], wb[(2 * 4 + cc) * CH + o], h[o]);
                    }
                }
                sum = x2.x;
            } else {
                // k = 0,1 taps from LDS
                #pragma unroll
                for (int k = 0; k < 2; ++k) {
                    const int jm = max(j - (2 - k) * dil, 0);
                    const float4 s0 = pl0[jm], s1 = pl1[jm], s2 = pl2[jm], s3 = pl3[jm];
                    const float4 x  = plx[jm];
                    const float tv[19] = {s0.x, s0.y, s0.z, s0.w, s1.x, s1.y, s1.z, s1.w,
                                          s2.x, s2.y, s2.z, s2.w, s3.x, s3.y, s3.z, s3.w,
                                          x.y, x.z, x.w};
                    #pragma unroll
                    for (int cc = 0; cc < 19; ++cc) {
                        #pragma unroll
                        for (int o = 0; o < CH; ++o)
                            h[o] = fmaf(tv[cc], wb[(k * 19 + cc) * CH + o], h[o]);
                    }
                }
                // k = 2 tap: own row from sn registers (+ controls from plx)
                #pragma unroll
                for (int cc = 0; cc < CH; ++cc) {
                    #pragma unroll
                    for (int o = 0; o < CH; ++o)
                        h[o] = fmaf(sn[cc], wb[(2 * 19 + cc) * CH + o], h[o]);
                }
                {
                    const float4 x2 = plx[max(j, 0)];
                    const float cv[3] = {x2.y, x2.z, x2.w};
                    #pragma unroll
                    for (int cc = 0; cc < 3; ++cc) {
                        #pragma unroll
                        for (int o = 0; o < CH; ++o)
                            h[o] = fmaf(cv[cc], wb[(2 * 19 + 16 + cc) * CH + o], h[o]);
                    }
                }
                sum = ((sn[0] + sn[1]) + (sn[2] + sn[3])) + ((sn[4] + sn[5]) + (sn[6] + sn[7]))
                    + ((sn[8] + sn[9]) + (sn[10] + sn[11])) + ((sn[12] + sn[13]) + (sn[14] + sn[15]));
            }
            #pragma unroll
            for (int o = 0; o < CH; ++o) h[o] = fmaxf(h[o], 0.f);

            const int r = buf_lo + j;
            if (j >= HALO && j < jmax && r >= TOFF) {   // mixer: valid mains only
                float d = 0.f;
                #pragma unroll
                for (int o = 0; o < CH; ++o) d = fmaf(h[o], mw[o], d);
                acc += d;
            }
            const float half = 0.5f * sum;              // io -> next signal (new sn)
            float ns[CH];
            #pragma unroll
            for (int o = 0; o < CH; ++o) ns[o] = ob[o] + half;
            #pragma unroll
            for (int cc = 0; cc < CH; ++cc) {
                #pragma unroll
                for (int o = 0; o < CH; ++o)
                    ns[o] = fmaf(h[cc], iw[cc * CH + o], ns[o]);
            }
            #pragma unroll
            for (int o = 0; o < CH; ++o) sn[o] = ns[o];
        };

        // wave-uniform activity (readfirstlane -> SGPR branch -> s_load weights)
        const bool w1 = (wave_first(j1) + 63 >= lo_off);
        const bool w0 = (wave_first(j0) + 63 >= lo_off);
        if (w1) do_row(j1, sn1, acc1);
        if (w0) do_row(j0, sn0, acc0);

        if (i != NL - 1) {
            __syncthreads();                            // reads done
            if (w1 && j1 >= lo_off && j1 < jmax) {
                pl0[j1] = make_float4(sn1[0],  sn1[1],  sn1[2],  sn1[3]);
                pl1[j1] = make_float4(sn1[4],  sn1[5],  sn1[6],  sn1[7]);
                pl2[j1] = make_float4(sn1[8],  sn1[9],  sn1[10], sn1[11]);
                pl3[j1] = make_float4(sn1[12], sn1[13], sn1[14], sn1[15]);
            }
            if (w0 && j0 >= lo_off && j0 < jmax) {
                pl0[j0] = make_float4(sn0[0],  sn0[1],  sn0[2],  sn0[3]);
                pl1[j0] = make_float4(sn0[4],  sn0[5],  sn0[6],  sn0[7]);
                pl2[j0] = make_float4(sn0[8],  sn0[9],  sn0[10], sn0[11]);
                pl3[j0] = make_float4(sn0[12], sn0[13], sn0[14], sn0[15]);
            }
            __syncthreads();                            // writes visible
        } else {
            if (j1 >= HALO && j1 < jmax) {              // mains -> global signal
                float* gp = sig_out + ((size_t)b * TFULL + (buf_lo + j1)) * CH;
                *(float4*)(gp + 0)  = make_float4(sn1[0],  sn1[1],  sn1[2],  sn1[3]);
                *(float4*)(gp + 4)  = make_float4(sn1[4],  sn1[5],  sn1[6],  sn1[7]);
                *(float4*)(gp + 8)  = make_float4(sn1[8],  sn1[9],  sn1[10], sn1[11]);
                *(float4*)(gp + 12) = make_float4(sn1[12], sn1[13], sn1[14], sn1[15]);
            }
            if (j0 >= HALO && j0 < jmax) {
                float* gp = sig_out + ((size_t)b * TFULL + (buf_lo + j0)) * CH;
                *(float4*)(gp + 0)  = make_float4(sn0[0],  sn0[1],  sn0[2],  sn0[3]);
                *(float4*)(gp + 4)  = make_float4(sn0[4],  sn0[5],  sn0[6],  sn0[7]);
                *(float4*)(gp + 8)  = make_float4(sn0[8],  sn0[9],  sn0[10], sn0[11]);
                *(float4*)(gp + 12) = make_float4(sn0[12], sn0[13], sn0[14], sn0[15]);
            }
        }
    }

    if (j0 >= HALO && j0 < jmax) {
        const int r = buf_lo + j0;
        if (r >= TOFF) {
            const size_t oi = (size_t)b * OUT_T + (r - TOFF);
            if constexpr (FIRSTG) out[oi] = mixer_b[0] + acc0; else out[oi] += acc0;
        }
    }
    if (j1 >= HALO && j1 < jmax) {
        const int r = buf_lo + j1;
        if (r >= TOFF) {
            const size_t oi = (size_t)b * OUT_T + (r - TOFF);
            if constexpr (FIRSTG) out[oi] = mixer_b[0] + acc1; else out[oi] += acc1;
        }
    }
}

// ---------------- unfused single layer (big dilation, zero halo), R7-proven ----------------
template<bool LASTL>
__global__ __launch_bounds__(256, 4) void single_layer(
    const float* __restrict__ input,    // (B,T,4)
    const float* __restrict__ sig_in,   // (B,T,16)
    const float* __restrict__ w,        // (3,19,16)
    const float* __restrict__ bias,     // (16)
    const float* __restrict__ iw,       // (16,16)   unused if LASTL
    const float* __restrict__ iob,      // (16)      unused if LASTL
    const float* __restrict__ mw,       // (16)
    float* __restrict__ sig_out,        // (B,T,16)  unused if LASTL
    float* __restrict__ out,            // (B,2048)
    int dil, int t0)
{
    const int b    = blockIdx.y;
    const int traw = t0 + blockIdx.x * 256 + threadIdx.x;
    const int t    = (traw < TFULL) ? traw : (TFULL - 1);   // clamp, guard stores
    const float* ib = input  + (size_t)b * TFULL * 4;
    const float* sb = sig_in + (size_t)b * TFULL * CH;

    const int tt0 = t - 2 * dil, tt1 = t - dil;
    const float4* sp0 = (const float4*)(sb + (size_t)tt0 * CH);
    const float4* sp1 = (const float4*)(sb + (size_t)tt1 * CH);
    const float4* sp2 = (const float4*)(sb + (size_t)t   * CH);
    const float4 a0 = sp0[0], a1 = sp0[1], a2 = sp0[2], a3 = sp0[3];
    const float4 b0 = sp1[0], b1 = sp1[1], b2 = sp1[2], b3 = sp1[3];
    const float4 c0 = sp2[0], c1 = sp2[1], c2 = sp2[2], c3 = sp2[3];
    const float4 x0 = *(const float4*)(ib + (size_t)tt0 * 4);
    const float4 x1 = *(const float4*)(ib + (size_t)tt1 * 4);
    const float4 x2 = *(const float4*)(ib + (size_t)t   * 4);

    float h[CH];
    #pragma unroll
    for (int o = 0; o < CH; ++o) h[o] = bias[o];

    const float t0v[19] = {a0.x,a0.y,a0.z,a0.w, a1.x,a1.y,a1.z,a1.w,
                           a2.x,a2.y,a2.z,a2.w, a3.x,a3.y,a3.z,a3.w,
                           x0.y,x0.z,x0.w};
    const float t1v[19] = {b0.x,b0.y,b0.z,b0.w, b1.x,b1.y,b1.z,b1.w,
                           b2.x,b2.y,b2.z,b2.w, b3.x,b3.y,b3.z,b3.w,
                           x1.y,x1.z,x1.w};
    const float t2v[19] = {c0.x,c0.y,c0.z,c0.w, c1.x,c1.y,c1.z,c1.w,
                           c2.x,c2.y,c2.z,c2.w, c3.x,c3.y,c3.z,c3.w,
                           x2.y,x2.z,x2.w};
    #pragma unroll
    for (int cc = 0; cc < 19; ++cc) {
        #pragma unroll
        for (int o = 0; o < CH; ++o) {
            h[o] = fmaf(t0v[cc], w[(0 * 19 + cc) * CH + o], h[o]);
            h[o] = fmaf(t1v[cc], w[(1 * 19 + cc) * CH + o], h[o]);
            h[o] = fmaf(t2v[cc], w[(2 * 19 + cc) * CH + o], h[o]);
        }
    }
    #pragma unroll
    for (int o = 0; o < CH; ++o) h[o] = fmaxf(h[o], 0.f);

    if (traw < TFULL && traw >= TOFF) {
        float m = 0.f;
        #pragma unroll
        for (int o = 0; o < CH; ++o) m = fmaf(h[o], mw[o], m);
        out[(size_t)b * OUT_T + (traw - TOFF)] += m;
    }

    if constexpr (!LASTL) {
        const float sum_t = ((c0.x + c0.y) + (c0.z + c0.w)) + ((c1.x + c1.y) + (c1.z + c1.w))
                          + ((c2.x + c2.y) + (c2.z + c2.w)) + ((c3.x + c3.y) + (c3.z + c3.w));
        float sn[CH];
        const float half = 0.5f * sum_t;
        #pragma unroll
        for (int o = 0; o < CH; ++o) sn[o] = iob[o] + half;
        #pragma unroll
        for (int cc = 0; cc < CH; ++cc) {
            #pragma unroll
            for (int o = 0; o < CH; ++o)
                sn[o] = fmaf(h[cc], iw[cc * CH + o], sn[o]);
        }
        if (traw < TFULL) {
            float* gp = sig_out + ((size_t)b * TFULL + traw) * CH;
            *(float4*)(gp + 0)  = make_float4(sn[0],  sn[1],  sn[2],  sn[3]);
            *(float4*)(gp + 4)  = make_float4(sn[4],  sn[5],  sn[6],  sn[7]);
            *(float4*)(gp + 8)  = make_float4(sn[8],  sn[9],  sn[10], sn[11]);
            *(float4*)(gp + 12) = make_float4(sn[12], sn[13], sn[14], sn[15]);
        }
    }
}

extern "C" void kernel_launch(void* const* d_in, const int* in_sizes, int n_in,
                              void* d_out, int out_size, void* d_ws, size_t ws_size,
                              hipStream_t stream) {
    const float* input   = (const float*)d_in[0];
    const float* conv_w0 = (const float*)d_in[1];
    const float* conv_w  = (const float*)d_in[2];
    const float* conv_b  = (const float*)d_in[3];
    const float* io_w    = (const float*)d_in[4];
    const float* io_b    = (const float*)d_in[5];
    const float* mixer_w = (const float*)d_in[6];
    const float* mixer_b = (const float*)d_in[7];
    float* out = (float*)d_out;

    float* s1 = (float*)d_ws;
    float* s2 = s1 + (size_t)NB * TFULL * CH;

    auto wl  = [&](int g) { return conv_w + (size_t)(g - 1) * 3 * 19 * CH; };
    auto bsl = [&](int g) { return conv_b + (size_t)g * CH; };
    auto iwl = [&](int g) { return io_w + (size_t)g * CH * CH; };
    auto ibl = [&](int g) { return io_b + (size_t)g * CH; };
    auto mwl = [&](int g) { return mixer_w + (size_t)g * CH; };

    dim3 blkG(GNT, 1, 1), blk256(256, 1, 1);

    // G_A: layers 0..6 (dil 1..64), halo 254, TILE 480, mains [254,4092) — R7 tiling
    group6_kernel<0, 7, 480, 254, true><<<dim3(8, NB), blkG, 0, stream>>>(
        input, conv_w0, conv_w, conv_b, io_w, io_b, mixer_w, mixer_b,
        nullptr, s1, out, 254);
    // L7 (dil 128): t in [510,4092) ; s1 -> s2
    single_layer<false><<<dim3(14, NB), blk256, 0, stream>>>(
        input, s1, wl(7), bsl(7), iwl(7), ibl(7), mwl(7), s2, out, 128, 510);
    // L8 (dil 256): t in [1022,4092) ; s2 -> s1
    single_layer<false><<<dim3(12, NB), blk256, 0, stream>>>(
        input, s2, wl(8), bsl(8), iwl(8), ibl(8), mwl(8), s1, out, 256, 1022);
    // G_D: layers 9..15 (dil 1..64), halo 254, TILE 352, mains [1276,4092) — R7 tiling
    group6_kernel<9, 7, 352, 254, false><<<dim3(8, NB), blkG, 0, stream>>>(
        input, conv_w0, conv_w, conv_b, io_w, io_b, mixer_w, mixer_b,
        s1, s2, out, 1276);
    // L16 (dil 128): t in [1532,4092) ; s2 -> s1
    single_layer<false><<<dim3(10, NB), blk256, 0, stream>>>(
        input, s2, wl(16), bsl(16), iwl(16), ibl(16), mwl(16), s1, out, 128, 1532);
    // L17 (dil 256): t in [2044,4092) ; s1 -> out only
    single_layer<true><<<dim3(8, NB), blk256, 0, stream>>>(
        input, s1, wl(17), bsl(17), nullptr, nullptr, mwl(17), nullptr, out, 256, 2044);
}